// Round 6
// baseline (2057.908 us; speedup 1.0000x reference)
//
#include <hip/hip_runtime.h>
#include <math.h>

// Model dims: H=512 D=128 L=8 T=64 W=240 CTX=60 NSTEPS=30

typedef __attribute__((ext_vector_type(8))) short short8;
typedef __attribute__((ext_vector_type(4))) float floatx4;

__device__ __forceinline__ float sigf(float x) { return 1.f / (1.f + __expf(-x)); }
__device__ __forceinline__ float tanh_f(float x) {
    float e = __expf(2.f * x);
    return 1.f - 2.f / (e + 1.f);
}
__device__ __forceinline__ unsigned short f2b(float x) {   // fp32 -> bf16 RNE
    unsigned u = __float_as_uint(x);
    unsigned r = (u + 0x7FFFu + ((u >> 16) & 1u)) >> 16;
    return (unsigned short)r;
}

// RELAXED agent-scope atomics everywhere (no acquire/release in hot loops —
// they emit buffer_inv / buffer_wbl2 on gfx950 and trash the XCD L2; R4->R5
// showed 1.5x from removing them). Flag publication ordering holds because
// every set_flag is preceded by __syncthreads() (vmcnt(0) drain for all waves).
__device__ __forceinline__ float gld(const float* p) {
    return __hip_atomic_load(p, __ATOMIC_RELAXED, __HIP_MEMORY_SCOPE_AGENT);
}
__device__ __forceinline__ void gst(float* p, float v) {
    __hip_atomic_store(p, v, __ATOMIC_RELAXED, __HIP_MEMORY_SCOPE_AGENT);
}
__device__ __forceinline__ unsigned long long gldll(const unsigned long long* p) {
    return __hip_atomic_load(p, __ATOMIC_RELAXED, __HIP_MEMORY_SCOPE_AGENT);
}
__device__ __forceinline__ void gstll(unsigned long long* p, unsigned long long v) {
    __hip_atomic_store(p, v, __ATOMIC_RELAXED, __HIP_MEMORY_SCOPE_AGENT);
}
__device__ __forceinline__ void set_flag(int* f, int v) {
    __hip_atomic_store(f, v, __ATOMIC_RELAXED, __HIP_MEMORY_SCOPE_AGENT);
}
__device__ __forceinline__ void wait_flag_ge(int* f, int ep) {
    while (__hip_atomic_load(f, __ATOMIC_RELAXED, __HIP_MEMORY_SCOPE_AGENT) < ep)
        __builtin_amdgcn_s_sleep(1);
}

// ---------------------------------------------------------------------------
// init: zero [hbufF | ph1 | ph2 | all flag arrays] = 147008 floats
// ---------------------------------------------------------------------------
__global__ void init_k(float* __restrict__ ws) {
    for (int i = blockIdx.x * blockDim.x + threadIdx.x; i < 147008; i += gridDim.x * blockDim.x)
        ws[i] = 0.f;
}

// ---------------------------------------------------------------------------
// Encoder, ONE persistent launch, 64 steps, bf16 MFMA (unchanged from R5).
// ---------------------------------------------------------------------------
__global__ void __launch_bounds__(256, 1) enc_all(
    const float* __restrict__ data,
    const float* __restrict__ Wih, const float* __restrict__ Whh,
    const float* __restrict__ bih, const float* __restrict__ bhh,
    unsigned long long* __restrict__ hbufF,   // [2][15][16][64] x (2 ull)
    float* __restrict__ henc,       // [240][512] fp32 final h
    int* __restrict__ flags)        // [240][32]
{
    __shared__ short act2[20 * 64 * 8];     // A-frags: [kt][lane][8 bf16]
    __shared__ float gw[4][640];            // per-wave gates [rr][f], stride 20
    __shared__ float cs[512];               // c[f*32 + local_dim]
    __shared__ short hw[4][16][8];          // h bf16 staging [w][f][dp]
    __shared__ float biasL[4][4][8];        // [w][g][dp]

    const int tid = threadIdx.x;
    const int fg = blockIdx.x >> 4, ds = blockIdx.x & 15;
    const int w = tid >> 6, lane = tid & 63;
    const int n = lane & 15, q = lane >> 4;

    short8 bfrag[2][20];
#pragma unroll
    for (int nt = 0; nt < 2; ++nt) {
        int rr = nt * 16 + n;
        int g = rr >> 3, dp = rr & 7;
        int grow = g * 512 + ds * 32 + w * 8 + dp;
#pragma unroll
        for (int kt = 0; kt < 20; ++kt) {
            int k0 = kt * 32 + q * 8;
            const float* src = (k0 < 512) ? (Whh + (size_t)grow * 512 + k0)
                                          : (Wih + (size_t)grow * 128 + (k0 - 512));
            float4 lo = *(const float4*)src;
            float4 hi = *(const float4*)(src + 4);
            short8 bf;
            bf[0] = (short)f2b(lo.x); bf[1] = (short)f2b(lo.y);
            bf[2] = (short)f2b(lo.z); bf[3] = (short)f2b(lo.w);
            bf[4] = (short)f2b(hi.x); bf[5] = (short)f2b(hi.y);
            bf[6] = (short)f2b(hi.z); bf[7] = (short)f2b(hi.w);
            bfrag[nt][kt] = bf;
        }
    }
    if (tid < 128) {
        int w2 = tid >> 5, rr = tid & 31;
        int g = rr >> 3, dp = rr & 7;
        int grow = g * 512 + ds * 32 + w2 * 8 + dp;
        biasL[w2][g][dp] = bih[grow] + bhh[grow];
    }
    for (int i = tid; i < 512; i += 256) cs[i] = 0.f;
    __syncthreads();

    unsigned long long* a2ll = (unsigned long long*)act2;

    for (int t = 0; t < 64; ++t) {
        if (t > 0) {
            if (tid < 16) wait_flag_ge(&flags[(fg * 16 + tid) * 32], t);
        }
        __syncthreads();

        {
            const unsigned long long* hsrc =
                hbufF + (size_t)(((t & 1) * 15 + fg) * 16) * 64 * 2;
            for (int i = tid; i < 2048; i += 256) a2ll[i] = gldll(hsrc + i);
            int kt2 = tid >> 6, l2 = tid & 63, f2 = l2 & 15, q2 = l2 >> 4;
            const float* xs = data + ((size_t)t * 240 + fg * 16 + f2) * 128 + kt2 * 32 + q2 * 8;
            float4 lo = *(const float4*)xs;
            float4 hi = *(const float4*)(xs + 4);
            short8 xp;
            xp[0] = (short)f2b(lo.x); xp[1] = (short)f2b(lo.y);
            xp[2] = (short)f2b(lo.z); xp[3] = (short)f2b(lo.w);
            xp[4] = (short)f2b(hi.x); xp[5] = (short)f2b(hi.y);
            xp[6] = (short)f2b(hi.z); xp[7] = (short)f2b(hi.w);
            *(short8*)&act2[((16 + kt2) * 64 + l2) * 8] = xp;
        }
        __syncthreads();

        floatx4 acc0 = {0.f, 0.f, 0.f, 0.f};
        floatx4 acc1 = {0.f, 0.f, 0.f, 0.f};
#pragma unroll
        for (int kt = 0; kt < 20; ++kt) {
            short8 a = *(short8*)&act2[(kt * 64 + lane) * 8];
            acc0 = __builtin_amdgcn_mfma_f32_16x16x32_bf16(a, bfrag[0][kt], acc0, 0, 0, 0);
            acc1 = __builtin_amdgcn_mfma_f32_16x16x32_bf16(a, bfrag[1][kt], acc1, 0, 0, 0);
        }
        *(floatx4*)&gw[w][(0 * 16 + n) * 20 + 4 * q] = acc0;
        *(floatx4*)&gw[w][(1 * 16 + n) * 20 + 4 * q] = acc1;

        int nb = (t + 1) & 1;
#pragma unroll
        for (int it = 0; it < 2; ++it) {
            int f = lane & 15, dp = q + 4 * it;
            float gi = gw[w][(0 * 8 + dp) * 20 + f] + biasL[w][0][dp];
            float gf = gw[w][(1 * 8 + dp) * 20 + f] + biasL[w][1][dp];
            float gg = gw[w][(2 * 8 + dp) * 20 + f] + biasL[w][2][dp];
            float go = gw[w][(3 * 8 + dp) * 20 + f] + biasL[w][3][dp];
            int ci = f * 32 + w * 8 + dp;
            float cc = cs[ci];
            float cn = sigf(gf) * cc + sigf(gi) * tanh_f(gg);
            float hn = sigf(go) * tanh_f(cn);
            cs[ci] = cn;
            hw[w][f][dp] = (short)f2b(hn);
            if (t == 63)
                gst(&henc[(size_t)(fg * 16 + f) * 512 + ds * 32 + w * 8 + dp], hn);
        }
        if (lane < 16) {
            const unsigned long long* hwp = (const unsigned long long*)&hw[w][lane][0];
            unsigned long long* dst =
                hbufF + (size_t)((((nb * 15 + fg) * 16 + ds) * 64) + w * 16 + lane) * 2;
            gstll(dst + 0, hwp[0]); gstll(dst + 1, hwp[1]);
        }
        __syncthreads();
        if (tid == 0) set_flag(&flags[(fg * 16 + ds) * 32], t + 1);
    }
}

// ---------------------------------------------------------------------------
// xp GEMM: C[M][2048] = A[M][K] @ Wv[2048][K]^T + ba + bb (rev flips A rows)
// ---------------------------------------------------------------------------
__global__ void __launch_bounds__(256) gemm_xp(
    const float* __restrict__ A, int M, int K, int rev,
    const float* __restrict__ Wv, const float* __restrict__ ba, const float* __restrict__ bb,
    float* __restrict__ C)
{
    __shared__ float At[16][66];
    __shared__ float Wt[128][66];
    const int tid = threadIdx.x;
    const int nt = blockIdx.x & 15, mt = blockIdx.x >> 4;
    const int rp = tid >> 2, fq = tid & 3;
    const int lr0 = 2 * rp, lr1 = lr0 + 1;
    const int n0 = nt * 128 + lr0, n1 = n0 + 1;

    float acc0[4], acc1[4];
    {
        float b0 = ba[n0] + bb[n0], b1 = ba[n1] + bb[n1];
#pragma unroll
        for (int j = 0; j < 4; ++j) { acc0[j] = b0; acc1[j] = b1; }
    }

    for (int kt = 0; kt < K; kt += 64) {
        {
            int f = tid >> 4, c4 = tid & 15;
            int m = mt * 16 + f;
            float4 v = make_float4(0.f, 0.f, 0.f, 0.f);
            if (m < M) {
                int ar = rev ? (M - 1 - m) : m;
                v = ((const float4*)(A + (size_t)ar * K + kt))[c4];
            }
            At[f][c4 * 4 + 0] = v.x; At[f][c4 * 4 + 1] = v.y;
            At[f][c4 * 4 + 2] = v.z; At[f][c4 * 4 + 3] = v.w;
        }
        for (int i = tid; i < 2048; i += 256) {
            int lr = i >> 4, c4 = i & 15;
            float4 v = ((const float4*)(Wv + (size_t)(nt * 128 + lr) * K + kt))[c4];
            Wt[lr][c4 * 4 + 0] = v.x; Wt[lr][c4 * 4 + 1] = v.y;
            Wt[lr][c4 * 4 + 2] = v.z; Wt[lr][c4 * 4 + 3] = v.w;
        }
        __syncthreads();
        const float2* w0p = (const float2*)(&Wt[lr0][0]);
        const float2* w1p = (const float2*)(&Wt[lr1][0]);
#pragma unroll 8
        for (int kh = 0; kh < 32; ++kh) {
            float2 w0 = w0p[kh], w1 = w1p[kh];
#pragma unroll
            for (int j = 0; j < 4; ++j) {
                float2 av = ((const float2*)(&At[4 * fq + j][0]))[kh];
                acc0[j] += w0.x * av.x + w0.y * av.y;
                acc1[j] += w1.x * av.x + w1.y * av.y;
            }
        }
        __syncthreads();
    }
#pragma unroll
    for (int j = 0; j < 4; ++j) {
        int m = mt * 16 + 4 * fq + j;
        if (m < M) {
            C[(size_t)m * 2048 + n0] = acc0[j];
            C[(size_t)m * 2048 + n1] = acc1[j];
        }
    }
}

// ---------------------------------------------------------------------------
// Pyramidal bi-LSTM recurrence. grid 128 = dir(2) x blk(64); 8 dims/block.
// Whh slice in REGISTERS with interleaved k-ownership (k = seg + 8j) so the
// LDS h reads are broadcast/conflict-free. xp gate prefetched before the wait.
// ---------------------------------------------------------------------------
__global__ void __launch_bounds__(256, 1) pyr_rec(
    const float* __restrict__ xpF, const float* __restrict__ xpB,
    const float* __restrict__ WhhF, const float* __restrict__ WhhB,
    float* __restrict__ hbuf,  // [buf2][dir2][512]
    float* __restrict__ outF, float* __restrict__ outB,
    int steps, int* __restrict__ flagF, int* __restrict__ flagB)
{
    const int tid = threadIdx.x;
    const int dir = blockIdx.x >> 6, blk = blockIdx.x & 63;
    const float* xp  = dir ? xpB : xpF;
    const float* Whh = dir ? WhhB : WhhF;
    float* outp = dir ? outB : outF;
    int* flag = dir ? flagB : flagF;

    __shared__ float hcur[512];
    __shared__ float red[32][9];
    __shared__ float gv[32];

    const int lr = tid & 31, seg = tid >> 5;           // row 0..31, k-seg 0..7
    const int grow = (lr >> 3) * 512 + blk * 8 + (lr & 7);
    float wl[64];
#pragma unroll
    for (int j = 0; j < 64; ++j) wl[j] = Whh[(size_t)grow * 512 + seg + 8 * j];

    const int growx = (tid >> 3) * 512 + blk * 8 + (tid & 7);   // for tid<32
    float creg = 0.f;
    __syncthreads();

    for (int t = 0; t < steps; ++t) {
        float xg = 0.f;
        if (tid < 32) xg = xp[(size_t)t * 2048 + growx];   // prefetch (no h dep)
        if (t > 0) {
            if (tid < 64) wait_flag_ge(&flag[tid * 32], t);
        }
        __syncthreads();
        int hb = t & 1;
        for (int i = tid; i < 512; i += 256)
            hcur[i] = gld(&hbuf[(hb * 2 + dir) * 512 + i]);
        __syncthreads();

        float a = 0.f;
#pragma unroll
        for (int j = 0; j < 64; ++j) a += wl[j] * hcur[seg + 8 * j];
        red[lr][seg] = a;
        __syncthreads();

        if (tid < 32) {
            float g = xg;
#pragma unroll
            for (int s2 = 0; s2 < 8; ++s2) g += red[tid][s2];
            gv[tid] = g;
        }
        __syncthreads();
        if (tid < 8) {
            float i_ = sigf(gv[tid]), f_ = sigf(gv[8 + tid]);
            float g_ = tanh_f(gv[16 + tid]), o_ = sigf(gv[24 + tid]);
            creg = f_ * creg + i_ * g_;
            float hn = o_ * tanh_f(creg);
            int d = blk * 8 + tid;
            gst(&hbuf[((1 - hb) * 2 + dir) * 512 + d], hn);
            int row = dir ? (steps - 1 - t) : t;
            outp[(size_t)row * 512 + d] = hn;
        }
        __syncthreads();   // drains vmcnt before flag set
        if (tid == 0) set_flag(&flag[blk * 32], t + 1);
    }
}

__global__ void x2_assemble(const float* __restrict__ f1, const float* __restrict__ b1o,
                            float* __restrict__ x2)
{
    int j = blockIdx.x;
    for (int k = threadIdx.x; k < 2048; k += 256) {
        int q = k >> 9, r = k & 511;
        const float* src = (q & 1) ? b1o : f1;
        int row = 2 * j + (q >> 1);
        x2[(size_t)j * 2048 + k] = src[(size_t)row * 512 + r];
    }
}

__global__ void ctx_k(const float* __restrict__ f2, const float* __restrict__ b2o,
                      float* __restrict__ ctx, float* __restrict__ hdec, float* __restrict__ inp)
{
    int j = blockIdx.x;
    for (int k = threadIdx.x; k < 1024; k += 256)
        ctx[(size_t)j * 1024 + k] = (k < 512) ? f2[(size_t)j * 512 + k]
                                              : b2o[(size_t)j * 512 + k - 512];
    if (j == 0) {
        for (int i = threadIdx.x; i < 512; i += 256) hdec[i] = f2[59 * 512 + i];
        if (threadIdx.x < 8) inp[threadIdx.x] = (threadIdx.x == 7) ? 1.f : 0.f;
    }
}

// ---------------------------------------------------------------------------
// Decoder: 66 blocks, 1 block/CU, register-resident weights.
// blocks 0/1: attn role — wa[130]+wo[16] regs, ctx half in LDS.
// blocks 2..65: GRU role — wg[64]+wi[64]+wc[33] regs (interleaved k-ownership
// => all LDS activation reads are broadcast or bank-spread; no pool).
// ---------------------------------------------------------------------------
__global__ void __launch_bounds__(256, 1) dec_k(
    const float* __restrict__ attn_W, const float* __restrict__ attn_b,
    const float* __restrict__ comb_W, const float* __restrict__ comb_b,
    const float* __restrict__ gWih, const float* __restrict__ gWhh,
    const float* __restrict__ gbih, const float* __restrict__ gbhh,
    const float* __restrict__ outW, const float* __restrict__ outb,
    const float* __restrict__ ctx,
    float* __restrict__ hdec, float* __restrict__ inp,
    float* __restrict__ applied, float* __restrict__ obuf,
    float* __restrict__ dout,
    int* __restrict__ flagA, int* __restrict__ flagB, int* __restrict__ flagC)
{
    const int tid = threadIdx.x, bid = blockIdx.x;
    __shared__ float ctxL[60 * 516];         // attn role only (124 KB)
    __shared__ float hl[512];
    __shared__ float xl[1040];               // [inp(8); applied(1024); pad(8)]
    __shared__ float inpl[8];
    __shared__ float redA[64][5];
    __shared__ float redG[32][9];
    __shared__ float redC[8][33];
    __shared__ float redO[8][33];
    __shared__ float ghl[24], gil[24];
    __shared__ float zz[64], aw[60], zd[8];
    __shared__ float ms[2];
    __shared__ float biasg[24], biasi[24], biasc[8];

    const bool attn_role = (bid < 2);
    const int gbid = bid - 2;
    const int dbase = gbid * 8;

    // ---- register weights ----
    float wa[130]; float wo[16];             // attn role
    float wg[64], wi[64], wc[33];            // gru role
    const int rz = tid >> 2, sz = tid & 3;   // attn z: 64 rows(60), 4 segs
    const int ro = tid >> 5, so = tid & 31;  // logits: 8 rows, 32 segs
    const int rg = tid >> 3, sg = tid & 7;   // gh/gi: 32 rows(24), 8 segs
    const int rc = tid >> 5, sc = tid & 31;  // comb: 8 rows, 32 segs

    if (attn_role) {
        int rr = (rz < 60) ? rz : 59;
#pragma unroll
        for (int i = 0; i < 130; ++i) wa[i] = attn_W[(size_t)rr * 520 + sz + 4 * i];
#pragma unroll
        for (int i = 0; i < 16; ++i) wo[i] = outW[(size_t)ro * 512 + so + 32 * i];
        for (int i = tid; i < 7680; i += 256) {
            int j = i >> 7, c4 = i & 127;
            float4 v = ((const float4*)(ctx + (size_t)j * 1024 + bid * 512))[c4];
            *(float4*)&ctxL[j * 516 + c4 * 4] = v;
        }
    } else {
        int rr = (rg < 24) ? rg : 23;
        int grow = (rr >> 3) * 512 + dbase + (rr & 7);
#pragma unroll
        for (int j = 0; j < 64; ++j) {
            wg[j] = gWhh[(size_t)grow * 512 + sg + 8 * j];
            wi[j] = gWih[(size_t)grow * 512 + sg + 8 * j];
        }
#pragma unroll
        for (int i = 0; i < 33; ++i) {
            int k = sc + 32 * i;
            wc[i] = (k < 1032) ? comb_W[(size_t)(dbase + rc) * 1032 + k] : 0.f;
        }
        if (tid < 24) {
            int g2 = (tid >> 3) * 512 + dbase + (tid & 7);
            biasg[tid] = gbhh[g2];
            biasi[tid] = gbih[g2];
        }
        if (tid < 8) biasc[tid] = comb_b[dbase + tid];
        if (tid < 8) xl[1032 + tid] = 0.f;     // pad so wc[i]*xl[k] is safe
    }
    __syncthreads();

    for (int s = 0; s < 30; ++s) {
        if (s > 0) {
            if (tid < 64) wait_flag_ge(&flagC[tid * 32], s);
        }
        __syncthreads();
        for (int i = tid; i < 512; i += 256) hl[i] = gld(&hdec[i]);
        __syncthreads();

        if (attn_role) {
            if (s > 0) {   // logits of previous step (uses current h)
                float a = 0.f;
#pragma unroll
                for (int i = 0; i < 16; ++i) a += wo[i] * hl[so + 32 * i];
                redO[ro][so] = a;
                __syncthreads();
                if (tid < 8) {
                    float a2 = outb[tid];
#pragma unroll
                    for (int g2 = 0; g2 < 32; ++g2) a2 += redO[tid][g2];
                    zd[tid] = a2;
                }
                __syncthreads();
                if (tid == 0) {
                    float m = zd[0];
                    for (int l = 1; l < 8; ++l) m = fmaxf(m, zd[l]);
                    float ss = 0.f;
                    for (int l = 0; l < 8; ++l) ss += __expf(zd[l] - m);
                    ms[0] = m + __logf(ss);
                }
                __syncthreads();
                if (tid < 8) {
                    float lp = zd[tid] - ms[0];
                    inpl[tid] = lp;
                    if (bid == 0) { dout[(s - 1) * 8 + tid] = lp; gst(&inp[tid], lp); }
                }
            } else {
                if (tid < 8) inpl[tid] = gld(&inp[tid]);
            }
            __syncthreads();
            {   // z = attn_W @ [inp; h] + attn_b ; thread k-set: k = sz + 4i
                float a = wa[0] * inpl[sz] + wa[1] * inpl[sz + 4];
#pragma unroll
                for (int i = 2; i < 130; ++i) a += wa[i] * hl[sz + 4 * i - 8];
                redA[rz][sz] = a;
            }
            __syncthreads();
            if (tid < 60)
                zz[tid] = attn_b[tid] + redA[tid][0] + redA[tid][1] + redA[tid][2] + redA[tid][3];
            __syncthreads();
            if (tid == 0) {
                float m = zz[0];
                for (int j = 1; j < 60; ++j) m = fmaxf(m, zz[j]);
                float ss = 0.f;
                for (int j = 0; j < 60; ++j) { float e = __expf(zz[j] - m); aw[j] = e; ss += e; }
                float inv = 1.f / ss;
                for (int j = 0; j < 60; ++j) aw[j] *= inv;
            }
            __syncthreads();
            for (int cc = tid; cc < 512; cc += 256) {
                float a = 0.f;
                for (int j = 0; j < 60; ++j) a += aw[j] * ctxL[j * 516 + cc];
                gst(&applied[bid * 512 + cc], a);
            }
            __syncthreads();   // drains vmcnt before flag set
            if (tid == 0) set_flag(&flagA[bid * 32], s + 1);
        } else {
            {   // gh = gWhh @ h ; k = sg + 8j (broadcast-friendly hl reads)
                float a = 0.f;
#pragma unroll
                for (int j = 0; j < 64; ++j) a += wg[j] * hl[sg + 8 * j];
                redG[rg][sg] = a;
            }
            __syncthreads();
            if (tid < 24) {
                float a = biasg[tid];
#pragma unroll
                for (int g2 = 0; g2 < 8; ++g2) a += redG[tid][g2];
                ghl[tid] = a;
            }
            if (tid < 2) wait_flag_ge(&flagA[tid * 32], s + 1);
            __syncthreads();
            if (tid < 8) xl[tid] = gld(&inp[tid]);
            for (int i = tid; i < 1024; i += 256) xl[8 + i] = gld(&applied[i]);
            __syncthreads();
            {   // o = relu(comb_W @ [inp; applied]) ; k = sc + 32i
                float b = 0.f;
#pragma unroll
                for (int i = 0; i < 33; ++i) b += wc[i] * xl[sc + 32 * i];
                redC[rc][sc] = b;
            }
            __syncthreads();
            if (tid < 8) {
                float a = biasc[tid];
#pragma unroll
                for (int g2 = 0; g2 < 32; ++g2) a += redC[tid][g2];
                gst(&obuf[dbase + tid], fmaxf(a, 0.f));
            }
            __syncthreads();   // drains vmcnt before flag set
            if (tid == 0) set_flag(&flagB[gbid * 32], s + 1);
            if (tid < 64) wait_flag_ge(&flagB[tid * 32], s + 1);
            __syncthreads();
            for (int i = tid; i < 512; i += 256) xl[i] = gld(&obuf[i]);
            __syncthreads();
            {   // gi = gWih @ o
                float a = 0.f;
#pragma unroll
                for (int j = 0; j < 64; ++j) a += wi[j] * xl[sg + 8 * j];
                redG[rg][sg] = a;
            }
            __syncthreads();
            if (tid < 24) {
                float a = biasi[tid];
#pragma unroll
                for (int g2 = 0; g2 < 8; ++g2) a += redG[tid][g2];
                gil[tid] = a;
            }
            __syncthreads();
            if (tid < 8) {
                float r_ = sigf(gil[tid] + ghl[tid]);
                float z_ = sigf(gil[8 + tid] + ghl[8 + tid]);
                float n_ = tanh_f(gil[16 + tid] + r_ * ghl[16 + tid]);
                float hnew = (1.f - z_) * n_ + z_ * hl[dbase + tid];
                gst(&hdec[dbase + tid], hnew);
            }
            __syncthreads();   // drains vmcnt before flag set
            if (tid == 0) set_flag(&flagC[gbid * 32], s + 1);
        }
    }

    // epilogue: logits for s=29
    if (bid == 0) {
        if (tid < 64) wait_flag_ge(&flagC[tid * 32], 30);
        __syncthreads();
        for (int i = tid; i < 512; i += 256) hl[i] = gld(&hdec[i]);
        __syncthreads();
        {
            float a = 0.f;
#pragma unroll
            for (int i = 0; i < 16; ++i) a += wo[i] * hl[so + 32 * i];
            redO[ro][so] = a;
        }
        __syncthreads();
        if (tid < 8) {
            float a = outb[tid];
#pragma unroll
            for (int g2 = 0; g2 < 32; ++g2) a += redO[tid][g2];
            zd[tid] = a;
        }
        __syncthreads();
        if (tid == 0) {
            float m = zd[0];
            for (int l = 1; l < 8; ++l) m = fmaxf(m, zd[l]);
            float ss = 0.f;
            for (int l = 0; l < 8; ++l) ss += __expf(zd[l] - m);
            ms[0] = m + __logf(ss);
        }
        __syncthreads();
        if (tid < 8) dout[29 * 8 + tid] = zd[tid] - ms[0];
    }
}

// ---------------------------------------------------------------------------
extern "C" void kernel_launch(void* const* d_in, const int* in_sizes, int n_in,
                              void* d_out, int out_size, void* d_ws, size_t ws_size,
                              hipStream_t stream) {
    (void)in_sizes; (void)n_in; (void)out_size; (void)ws_size;
    const float* data    = (const float*)d_in[0];
    const float* enc_Wih = (const float*)d_in[1];
    const float* enc_Whh = (const float*)d_in[2];
    const float* enc_bih = (const float*)d_in[3];
    const float* enc_bhh = (const float*)d_in[4];
    const float* p1f_Wih = (const float*)d_in[5];
    const float* p1f_Whh = (const float*)d_in[6];
    const float* p1f_bih = (const float*)d_in[7];
    const float* p1f_bhh = (const float*)d_in[8];
    const float* p1b_Wih = (const float*)d_in[9];
    const float* p1b_Whh = (const float*)d_in[10];
    const float* p1b_bih = (const float*)d_in[11];
    const float* p1b_bhh = (const float*)d_in[12];
    const float* p2f_Wih = (const float*)d_in[13];
    const float* p2f_Whh = (const float*)d_in[14];
    const float* p2f_bih = (const float*)d_in[15];
    const float* p2f_bhh = (const float*)d_in[16];
    const float* p2b_Wih = (const float*)d_in[17];
    const float* p2b_Whh = (const float*)d_in[18];
    const float* p2b_bih = (const float*)d_in[19];
    const float* p2b_bhh = (const float*)d_in[20];
    const float* attn_W  = (const float*)d_in[21];
    const float* attn_b  = (const float*)d_in[22];
    const float* comb_W  = (const float*)d_in[23];
    const float* comb_b  = (const float*)d_in[24];
    const float* gru_Wih = (const float*)d_in[25];
    const float* gru_Whh = (const float*)d_in[26];
    const float* gru_bih = (const float*)d_in[27];
    const float* gru_bhh = (const float*)d_in[28];
    const float* out_W   = (const float*)d_in[29];
    const float* out_b   = (const float*)d_in[30];

    float* ws = (float*)d_ws;
    // zeroed region [0 .. 147008)
    unsigned long long* hbufF = (unsigned long long*)ws;  // 122880 words
    float* ph1      = ws + 122880;           // 2048
    float* ph2      = ws + 124928;           // 2048
    int* flagsE     = (int*)(ws + 126976);   // 7680
    int* flagsP1F   = (int*)(ws + 134656);   // 2048
    int* flagsP1B   = (int*)(ws + 136704);   // 2048
    int* flagsP2F   = (int*)(ws + 138752);   // 2048
    int* flagsP2B   = (int*)(ws + 140800);   // 2048
    int* flagsDA    = (int*)(ws + 142848);   // 64
    int* flagsDB    = (int*)(ws + 142912);   // 2048
    int* flagsDC    = (int*)(ws + 144960);   // 2048  -> zero end = 147008
    // non-zeroed scratch
    float* henc  = ws + 147008;              // 122880
    float* xp1f  = ws + 269888;              // 245760
    float* xp1b  = ws + 515648;              // 245760
    float* f1    = ws + 761408;              // 61440
    float* b1o   = ws + 822848;              // 61440
    float* x2    = ws + 884288;              // 122880
    float* xp2f  = ws + 1007168;             // 122880
    float* xp2b  = ws + 1130048;             // 122880
    float* f2    = ws + 1252928;             // 30720
    float* b2o   = ws + 1283648;             // 30720
    float* ctxb  = ws + 1314368;             // 61440
    float* hdec  = ws + 1375808;             // 512
    float* inp   = ws + 1376320;             // 16
    float* appl  = ws + 1376336;             // 1024
    float* obuf  = ws + 1377360;             // 512

    init_k<<<256, 256, 0, stream>>>(ws);

    enc_all<<<240, 256, 0, stream>>>(data, enc_Wih, enc_Whh, enc_bih, enc_bhh,
                                     hbufF, henc, flagsE);
    gemm_xp<<<128, 256, 0, stream>>>(henc, 120, 1024, 0, p1f_Wih, p1f_bih, p1f_bhh, xp1f);
    gemm_xp<<<128, 256, 0, stream>>>(henc, 120, 1024, 1, p1b_Wih, p1b_bih, p1b_bhh, xp1b);
    pyr_rec<<<128, 256, 0, stream>>>(xp1f, xp1b, p1f_Whh, p1b_Whh, ph1, f1, b1o, 120,
                                     flagsP1F, flagsP1B);
    x2_assemble<<<60, 256, 0, stream>>>(f1, b1o, x2);
    gemm_xp<<<64, 256, 0, stream>>>(x2, 60, 2048, 0, p2f_Wih, p2f_bih, p2f_bhh, xp2f);
    gemm_xp<<<64, 256, 0, stream>>>(x2, 60, 2048, 1, p2b_Wih, p2b_bih, p2b_bhh, xp2b);
    pyr_rec<<<128, 256, 0, stream>>>(xp2f, xp2b, p2f_Whh, p2b_Whh, ph2, f2, b2o, 60,
                                     flagsP2F, flagsP2B);
    ctx_k<<<60, 256, 0, stream>>>(f2, b2o, ctxb, hdec, inp);
    dec_k<<<66, 256, 0, stream>>>(attn_W, attn_b, comb_W, comb_b,
                                  gru_Wih, gru_Whh, gru_bih, gru_bhh,
                                  out_W, out_b, ctxb, hdec, inp, appl, obuf,
                                  (float*)d_out, flagsDA, flagsDB, flagsDC);
}

// Round 7
// 1866.696 us; speedup vs baseline: 1.1024x; 1.1024x over previous
//
#include <hip/hip_runtime.h>
#include <math.h>

// Model dims: H=512 D=128 L=8 T=64 W=240 CTX=60 NSTEPS=30

typedef __attribute__((ext_vector_type(8))) short short8;
typedef __attribute__((ext_vector_type(4))) float floatx4;
typedef unsigned long long ull;

__device__ __forceinline__ float sigf(float x) { return 1.f / (1.f + __expf(-x)); }
__device__ __forceinline__ float tanh_f(float x) {
    float e = __expf(2.f * x);
    return 1.f - 2.f / (e + 1.f);
}
__device__ __forceinline__ unsigned short f2b(float x) {   // fp32 -> bf16 RNE
    unsigned u = __float_as_uint(x);
    unsigned r = (u + 0x7FFFu + ((u >> 16) & 1u)) >> 16;
    return (unsigned short)r;
}

// RELAXED agent-scope atomics only (acquire/release emit buffer_inv/wbl2 on
// gfx950 and trash the XCD L2 — R4->R5 lesson). Cross-block payloads are
// published as ONE 8-byte word {epoch|data}: consumer polls the word itself,
// so data+readiness arrive in a single MALL round-trip (vs flag RT + data RT).
__device__ __forceinline__ float gld(const float* p) {
    return __hip_atomic_load(p, __ATOMIC_RELAXED, __HIP_MEMORY_SCOPE_AGENT);
}
__device__ __forceinline__ void gst(float* p, float v) {
    __hip_atomic_store(p, v, __ATOMIC_RELAXED, __HIP_MEMORY_SCOPE_AGENT);
}
__device__ __forceinline__ ull gldll(const ull* p) {
    return __hip_atomic_load(p, __ATOMIC_RELAXED, __HIP_MEMORY_SCOPE_AGENT);
}
__device__ __forceinline__ void gstll(ull* p, ull v) {
    __hip_atomic_store(p, v, __ATOMIC_RELAXED, __HIP_MEMORY_SCOPE_AGENT);
}
__device__ __forceinline__ ull packfe(float d, int ep) {
    return ((ull)(unsigned)ep << 32) | (ull)__float_as_uint(d);
}
__device__ __forceinline__ float waitfe(const ull* p, int ep) {
    ull v = gldll(p);
    while ((int)(v >> 32) != ep) v = gldll(p);
    return __uint_as_float((unsigned)v);
}
__device__ __forceinline__ void set_flag(int* f, int v) {
    __hip_atomic_store(f, v, __ATOMIC_RELAXED, __HIP_MEMORY_SCOPE_AGENT);
}
__device__ __forceinline__ void wait_flag_ge(int* f, int ep) {
    while (__hip_atomic_load(f, __ATOMIC_RELAXED, __HIP_MEMORY_SCOPE_AGENT) < ep)
        __builtin_amdgcn_s_sleep(1);
}

// ---------------------------------------------------------------------------
// init: zero [hbufF | flagsE | hp1 | hp2 | hdec_p | app_p | obuf_p] = 142864 f
// ---------------------------------------------------------------------------
__global__ void init_k(float* __restrict__ ws) {
    for (int i = blockIdx.x * blockDim.x + threadIdx.x; i < 142864; i += gridDim.x * blockDim.x)
        ws[i] = 0.f;
}

// ---------------------------------------------------------------------------
// Encoder, ONE persistent launch, 64 steps, bf16 MFMA (unchanged from R6).
// ---------------------------------------------------------------------------
__global__ void __launch_bounds__(256, 1) enc_all(
    const float* __restrict__ data,
    const float* __restrict__ Wih, const float* __restrict__ Whh,
    const float* __restrict__ bih, const float* __restrict__ bhh,
    ull* __restrict__ hbufF,        // [2][15][16][64] x (2 ull)
    float* __restrict__ henc,       // [240][512] fp32 final h
    int* __restrict__ flags)        // [240][32]
{
    __shared__ short act2[20 * 64 * 8];
    __shared__ float gw[4][640];
    __shared__ float cs[512];
    __shared__ short hw[4][16][8];
    __shared__ float biasL[4][4][8];

    const int tid = threadIdx.x;
    const int fg = blockIdx.x >> 4, ds = blockIdx.x & 15;
    const int w = tid >> 6, lane = tid & 63;
    const int n = lane & 15, q = lane >> 4;

    short8 bfrag[2][20];
#pragma unroll
    for (int nt = 0; nt < 2; ++nt) {
        int rr = nt * 16 + n;
        int g = rr >> 3, dp = rr & 7;
        int grow = g * 512 + ds * 32 + w * 8 + dp;
#pragma unroll
        for (int kt = 0; kt < 20; ++kt) {
            int k0 = kt * 32 + q * 8;
            const float* src = (k0 < 512) ? (Whh + (size_t)grow * 512 + k0)
                                          : (Wih + (size_t)grow * 128 + (k0 - 512));
            float4 lo = *(const float4*)src;
            float4 hi = *(const float4*)(src + 4);
            short8 bf;
            bf[0] = (short)f2b(lo.x); bf[1] = (short)f2b(lo.y);
            bf[2] = (short)f2b(lo.z); bf[3] = (short)f2b(lo.w);
            bf[4] = (short)f2b(hi.x); bf[5] = (short)f2b(hi.y);
            bf[6] = (short)f2b(hi.z); bf[7] = (short)f2b(hi.w);
            bfrag[nt][kt] = bf;
        }
    }
    if (tid < 128) {
        int w2 = tid >> 5, rr = tid & 31;
        int g = rr >> 3, dp = rr & 7;
        int grow = g * 512 + ds * 32 + w2 * 8 + dp;
        biasL[w2][g][dp] = bih[grow] + bhh[grow];
    }
    for (int i = tid; i < 512; i += 256) cs[i] = 0.f;
    __syncthreads();

    ull* a2ll = (ull*)act2;

    for (int t = 0; t < 64; ++t) {
        if (t > 0) {
            if (tid < 16) wait_flag_ge(&flags[(fg * 16 + tid) * 32], t);
        }
        __syncthreads();

        {
            const ull* hsrc = hbufF + (size_t)(((t & 1) * 15 + fg) * 16) * 64 * 2;
            for (int i = tid; i < 2048; i += 256) a2ll[i] = gldll(hsrc + i);
            int kt2 = tid >> 6, l2 = tid & 63, f2 = l2 & 15, q2 = l2 >> 4;
            const float* xs = data + ((size_t)t * 240 + fg * 16 + f2) * 128 + kt2 * 32 + q2 * 8;
            float4 lo = *(const float4*)xs;
            float4 hi = *(const float4*)(xs + 4);
            short8 xp;
            xp[0] = (short)f2b(lo.x); xp[1] = (short)f2b(lo.y);
            xp[2] = (short)f2b(lo.z); xp[3] = (short)f2b(lo.w);
            xp[4] = (short)f2b(hi.x); xp[5] = (short)f2b(hi.y);
            xp[6] = (short)f2b(hi.z); xp[7] = (short)f2b(hi.w);
            *(short8*)&act2[((16 + kt2) * 64 + l2) * 8] = xp;
        }
        __syncthreads();

        floatx4 acc0 = {0.f, 0.f, 0.f, 0.f};
        floatx4 acc1 = {0.f, 0.f, 0.f, 0.f};
#pragma unroll
        for (int kt = 0; kt < 20; ++kt) {
            short8 a = *(short8*)&act2[(kt * 64 + lane) * 8];
            acc0 = __builtin_amdgcn_mfma_f32_16x16x32_bf16(a, bfrag[0][kt], acc0, 0, 0, 0);
            acc1 = __builtin_amdgcn_mfma_f32_16x16x32_bf16(a, bfrag[1][kt], acc1, 0, 0, 0);
        }
        *(floatx4*)&gw[w][(0 * 16 + n) * 20 + 4 * q] = acc0;
        *(floatx4*)&gw[w][(1 * 16 + n) * 20 + 4 * q] = acc1;

        int nb = (t + 1) & 1;
#pragma unroll
        for (int it = 0; it < 2; ++it) {
            int f = lane & 15, dp = q + 4 * it;
            float gi = gw[w][(0 * 8 + dp) * 20 + f] + biasL[w][0][dp];
            float gf = gw[w][(1 * 8 + dp) * 20 + f] + biasL[w][1][dp];
            float gg = gw[w][(2 * 8 + dp) * 20 + f] + biasL[w][2][dp];
            float go = gw[w][(3 * 8 + dp) * 20 + f] + biasL[w][3][dp];
            int ci = f * 32 + w * 8 + dp;
            float cc = cs[ci];
            float cn = sigf(gf) * cc + sigf(gi) * tanh_f(gg);
            float hn = sigf(go) * tanh_f(cn);
            cs[ci] = cn;
            hw[w][f][dp] = (short)f2b(hn);
            if (t == 63)
                gst(&henc[(size_t)(fg * 16 + f) * 512 + ds * 32 + w * 8 + dp], hn);
        }
        if (lane < 16) {
            const ull* hwp = (const ull*)&hw[w][lane][0];
            ull* dst = hbufF + (size_t)((((nb * 15 + fg) * 16 + ds) * 64) + w * 16 + lane) * 2;
            gstll(dst + 0, hwp[0]); gstll(dst + 1, hwp[1]);
        }
        __syncthreads();
        if (tid == 0) set_flag(&flags[(fg * 16 + ds) * 32], t + 1);
    }
}

// ---------------------------------------------------------------------------
// xp GEMM (unchanged)
// ---------------------------------------------------------------------------
__global__ void __launch_bounds__(256) gemm_xp(
    const float* __restrict__ A, int M, int K, int rev,
    const float* __restrict__ Wv, const float* __restrict__ ba, const float* __restrict__ bb,
    float* __restrict__ C)
{
    __shared__ float At[16][66];
    __shared__ float Wt[128][66];
    const int tid = threadIdx.x;
    const int nt = blockIdx.x & 15, mt = blockIdx.x >> 4;
    const int rp = tid >> 2, fq = tid & 3;
    const int lr0 = 2 * rp, lr1 = lr0 + 1;
    const int n0 = nt * 128 + lr0, n1 = n0 + 1;

    float acc0[4], acc1[4];
    {
        float b0 = ba[n0] + bb[n0], b1 = ba[n1] + bb[n1];
#pragma unroll
        for (int j = 0; j < 4; ++j) { acc0[j] = b0; acc1[j] = b1; }
    }

    for (int kt = 0; kt < K; kt += 64) {
        {
            int f = tid >> 4, c4 = tid & 15;
            int m = mt * 16 + f;
            float4 v = make_float4(0.f, 0.f, 0.f, 0.f);
            if (m < M) {
                int ar = rev ? (M - 1 - m) : m;
                v = ((const float4*)(A + (size_t)ar * K + kt))[c4];
            }
            At[f][c4 * 4 + 0] = v.x; At[f][c4 * 4 + 1] = v.y;
            At[f][c4 * 4 + 2] = v.z; At[f][c4 * 4 + 3] = v.w;
        }
        for (int i = tid; i < 2048; i += 256) {
            int lr = i >> 4, c4 = i & 15;
            float4 v = ((const float4*)(Wv + (size_t)(nt * 128 + lr) * K + kt))[c4];
            Wt[lr][c4 * 4 + 0] = v.x; Wt[lr][c4 * 4 + 1] = v.y;
            Wt[lr][c4 * 4 + 2] = v.z; Wt[lr][c4 * 4 + 3] = v.w;
        }
        __syncthreads();
        const float2* w0p = (const float2*)(&Wt[lr0][0]);
        const float2* w1p = (const float2*)(&Wt[lr1][0]);
#pragma unroll 8
        for (int kh = 0; kh < 32; ++kh) {
            float2 w0 = w0p[kh], w1 = w1p[kh];
#pragma unroll
            for (int j = 0; j < 4; ++j) {
                float2 av = ((const float2*)(&At[4 * fq + j][0]))[kh];
                acc0[j] += w0.x * av.x + w0.y * av.y;
                acc1[j] += w1.x * av.x + w1.y * av.y;
            }
        }
        __syncthreads();
    }
#pragma unroll
    for (int j = 0; j < 4; ++j) {
        int m = mt * 16 + 4 * fq + j;
        if (m < M) {
            C[(size_t)m * 2048 + n0] = acc0[j];
            C[(size_t)m * 2048 + n1] = acc1[j];
        }
    }
}

// ---------------------------------------------------------------------------
// Pyramidal bi-LSTM. grid 128 = dir(2) x blk(64); 8 dims/block.
// h exchanged as {epoch|float} ull words, parity double-buffered:
// hp[dir][parity][512]. One MALL RT per step. Weights in regs, float4
// mod-32 interleave (k = 4*seg + 32*j + r): coalesced preload + conflict-free
// broadcast LDS reads.
// ---------------------------------------------------------------------------
__global__ void __launch_bounds__(256, 1) pyr_rec(
    const float* __restrict__ xpF, const float* __restrict__ xpB,
    const float* __restrict__ WhhF, const float* __restrict__ WhhB,
    ull* __restrict__ hp,      // [dir][2][512]
    float* __restrict__ outF, float* __restrict__ outB,
    int steps)
{
    const int tid = threadIdx.x;
    const int dir = blockIdx.x >> 6, blk = blockIdx.x & 63;
    const float* xp  = dir ? xpB : xpF;
    const float* Whh = dir ? WhhB : WhhF;
    float* outp = dir ? outB : outF;
    ull* hpd = hp + (size_t)dir * 1024;

    __shared__ __align__(16) float hcur[512];
    __shared__ float red[32][9];
    __shared__ float gv[32];

    const int lr = tid & 31, seg = tid >> 5;
    const int grow = (lr >> 3) * 512 + blk * 8 + (lr & 7);
    float4 wl4[16];
#pragma unroll
    for (int j = 0; j < 16; ++j)
        wl4[j] = *(const float4*)&Whh[(size_t)grow * 512 + 4 * seg + 32 * j];

    const int growx = (tid >> 3) * 512 + blk * 8 + (tid & 7);   // for tid<32
    float creg = 0.f;
    __syncthreads();

    for (int t = 0; t < steps; ++t) {
        float xg = 0.f;
        if (tid < 32) xg = xp[(size_t)t * 2048 + growx];   // prefetch (no h dep)
        int p = t & 1;
        for (int c = tid; c < 512; c += 256)
            hcur[c] = waitfe(&hpd[p * 512 + c], t);
        __syncthreads();

        float a = 0.f;
#pragma unroll
        for (int j = 0; j < 16; ++j) {
            float4 w = wl4[j];
            float4 h4 = *(const float4*)&hcur[4 * seg + 32 * j];
            a += w.x*h4.x + w.y*h4.y + w.z*h4.z + w.w*h4.w;
        }
        red[lr][seg] = a;
        __syncthreads();

        if (tid < 32) {
            float g = xg;
#pragma unroll
            for (int s2 = 0; s2 < 8; ++s2) g += red[tid][s2];
            gv[tid] = g;
        }
        __syncthreads();
        if (tid < 8) {
            float i_ = sigf(gv[tid]), f_ = sigf(gv[8 + tid]);
            float g_ = tanh_f(gv[16 + tid]), o_ = sigf(gv[24 + tid]);
            creg = f_ * creg + i_ * g_;
            float hn = o_ * tanh_f(creg);
            int d = blk * 8 + tid;
            gstll(&hpd[((t + 1) & 1) * 512 + d], packfe(hn, t + 1));
            int row = dir ? (steps - 1 - t) : t;
            outp[(size_t)row * 512 + d] = hn;
        }
        __syncthreads();
    }
}

__global__ void x2_assemble(const float* __restrict__ f1, const float* __restrict__ b1o,
                            float* __restrict__ x2)
{
    int j = blockIdx.x;
    for (int k = threadIdx.x; k < 2048; k += 256) {
        int q = k >> 9, r = k & 511;
        const float* src = (q & 1) ? b1o : f1;
        int row = 2 * j + (q >> 1);
        x2[(size_t)j * 2048 + k] = src[(size_t)row * 512 + r];
    }
}

// ctx assemble + publish hdec chunks with epoch 0
__global__ void ctx_k(const float* __restrict__ f2, const float* __restrict__ b2o,
                      float* __restrict__ ctx, ull* __restrict__ hdec_p)
{
    int j = blockIdx.x;
    for (int k = threadIdx.x; k < 1024; k += 256)
        ctx[(size_t)j * 1024 + k] = (k < 512) ? f2[(size_t)j * 512 + k]
                                              : b2o[(size_t)j * 512 + k - 512];
    if (j == 0) {
        for (int i = threadIdx.x; i < 512; i += 256)
            hdec_p[i] = packfe(f2[59 * 512 + i], 0);
    }
}

// ---------------------------------------------------------------------------
// Decoder: 66 blocks, 1 block/CU, register weights (float4 mod-N interleave).
// All cross-block payloads are {epoch|data} ull words, single-slot (safety
// proven via the applied->obuf->h gating chain). 3 one-RT hops per step.
// ---------------------------------------------------------------------------
__global__ void __launch_bounds__(256, 1) dec_k(
    const float* __restrict__ attn_W, const float* __restrict__ attn_b,
    const float* __restrict__ comb_W, const float* __restrict__ comb_b,
    const float* __restrict__ gWih, const float* __restrict__ gWhh,
    const float* __restrict__ gbih, const float* __restrict__ gbhh,
    const float* __restrict__ outW, const float* __restrict__ outb,
    const float* __restrict__ ctx,
    ull* __restrict__ hdec_p,   // [512]
    ull* __restrict__ app_p,    // [1032] = inp(8) + applied(1024)
    ull* __restrict__ obuf_p,   // [512]
    float* __restrict__ dout)
{
    const int tid = threadIdx.x, bid = blockIdx.x;
    __shared__ float ctxL[60 * 516];                 // attn role
    __shared__ __align__(16) float hx[528];          // [inpl(8); h(512); pad0(8)]
    __shared__ __align__(16) float xl[1160];         // [inp(8); applied(1024); pad0]
    __shared__ float redA[64][5];
    __shared__ float redG[32][9];
    __shared__ float redC[8][33];
    __shared__ float redO[8][33];
    __shared__ float ghl[24], gil[24];
    __shared__ float zz[64], aw[60], zd[8];
    __shared__ float ms[1];
    __shared__ float biasg[24], biasi[24], biasc[8];

    const bool attn_role = (bid < 2);
    const int gbid = bid - 2;
    const int dbase = gbid * 8;

    float4 wa4[33]; float4 wo4[4];          // attn role
    float4 wg4[16], wi4[16], wc4[9];        // gru role
    const int rz = tid >> 2, sz = tid & 3;  // z: rows(60/64), 4 segs
    const int ro = tid >> 5, so = tid & 31; // logits: 8 rows, 32 segs
    const int rg = tid >> 3, sg = tid & 7;  // gh/gi: rows(24/32), 8 segs
    const int rc = tid >> 5, sc = tid & 31; // comb: 8 rows, 32 segs

    if (attn_role) {
        int rr = (rz < 60) ? rz : 59;
#pragma unroll
        for (int i = 0; i < 32; ++i)
            wa4[i] = *(const float4*)&attn_W[(size_t)rr * 520 + 4 * sz + 16 * i];
        {
            float* wap = (float*)&wa4[32];
#pragma unroll
            for (int r = 0; r < 4; ++r) {
                int k = 4 * sz + 512 + r;
                wap[r] = (k < 520) ? attn_W[(size_t)rr * 520 + k] : 0.f;
            }
        }
#pragma unroll
        for (int i = 0; i < 4; ++i)
            wo4[i] = *(const float4*)&outW[(size_t)ro * 512 + 4 * so + 128 * i];
        for (int i = tid; i < 7680; i += 256) {
            int j = i >> 7, c4 = i & 127;
            float4 v = ((const float4*)(ctx + (size_t)j * 1024 + bid * 512))[c4];
            *(float4*)&ctxL[j * 516 + c4 * 4] = v;
        }
        if (tid < 8) hx[520 + tid] = 0.f;
    } else {
        int rr = (rg < 24) ? rg : 23;
        int grow = (rr >> 3) * 512 + dbase + (rr & 7);
#pragma unroll
        for (int j = 0; j < 16; ++j) {
            wg4[j] = *(const float4*)&gWhh[(size_t)grow * 512 + 4 * sg + 32 * j];
            wi4[j] = *(const float4*)&gWih[(size_t)grow * 512 + 4 * sg + 32 * j];
        }
#pragma unroll
        for (int i = 0; i < 8; ++i)
            wc4[i] = *(const float4*)&comb_W[(size_t)(dbase + rc) * 1032 + 4 * sc + 128 * i];
        {
            float* wcp = (float*)&wc4[8];
#pragma unroll
            for (int r = 0; r < 4; ++r) {
                int k = 4 * sc + 1024 + r;
                wcp[r] = (k < 1032) ? comb_W[(size_t)(dbase + rc) * 1032 + k] : 0.f;
            }
        }
        if (tid < 24) {
            int g2 = (tid >> 3) * 512 + dbase + (tid & 7);
            biasg[tid] = gbhh[g2];
            biasi[tid] = gbih[g2];
        }
        if (tid < 8) biasc[tid] = comb_b[dbase + tid];
        for (int i = tid; i < 128; i += 256) xl[1032 + i] = 0.f;
    }
    __syncthreads();

    for (int s = 0; s < 30; ++s) {
        // ---- hop 1: h (epoch s) ----
        for (int c = tid; c < 512; c += 256)
            hx[8 + c] = waitfe(&hdec_p[c], s);
        __syncthreads();

        if (attn_role) {
            if (s > 0) {   // logits of previous step
                {
                    float a = 0.f;
#pragma unroll
                    for (int i = 0; i < 4; ++i) {
                        float4 w = wo4[i];
                        float4 h4 = *(const float4*)&hx[8 + 4 * so + 128 * i];
                        a += w.x*h4.x + w.y*h4.y + w.z*h4.z + w.w*h4.w;
                    }
                    redO[ro][so] = a;
                }
                __syncthreads();
                if (tid < 8) {
                    float a = outb[tid];
#pragma unroll
                    for (int g2 = 0; g2 < 32; ++g2) a += redO[tid][g2];
                    zd[tid] = a;
                }
                __syncthreads();
                if (tid == 0) {
                    float m = zd[0];
                    for (int l = 1; l < 8; ++l) m = fmaxf(m, zd[l]);
                    float ss = 0.f;
                    for (int l = 0; l < 8; ++l) ss += __expf(zd[l] - m);
                    ms[0] = m + __logf(ss);
                }
                __syncthreads();
                if (tid < 8) {
                    float lp = zd[tid] - ms[0];
                    hx[tid] = lp;
                    if (bid == 0) {
                        dout[(s - 1) * 8 + tid] = lp;
                        gstll(&app_p[tid], packfe(lp, s + 1));
                    }
                }
            } else {
                if (tid < 8) {
                    float v = (tid == 7) ? 1.f : 0.f;
                    hx[tid] = v;
                    if (bid == 0) gstll(&app_p[tid], packfe(v, 1));
                }
            }
            __syncthreads();
            {   // z = attn_W @ [inp; h] ; k = 4sz + 16i + r over hx[0..520)
                float a = 0.f;
#pragma unroll
                for (int i = 0; i < 33; ++i) {
                    float4 w = wa4[i];
                    float4 x4 = *(const float4*)&hx[4 * sz + 16 * i];
                    a += w.x*x4.x + w.y*x4.y + w.z*x4.z + w.w*x4.w;
                }
                redA[rz][sz] = a;
            }
            __syncthreads();
            if (tid < 60)
                zz[tid] = attn_b[tid] + redA[tid][0] + redA[tid][1] + redA[tid][2] + redA[tid][3];
            __syncthreads();
            if (tid == 0) {
                float m = zz[0];
                for (int j = 1; j < 60; ++j) m = fmaxf(m, zz[j]);
                float ss = 0.f;
                for (int j = 0; j < 60; ++j) { float e = __expf(zz[j] - m); aw[j] = e; ss += e; }
                float inv = 1.f / ss;
                for (int j = 0; j < 60; ++j) aw[j] *= inv;
            }
            __syncthreads();
            for (int cc = tid; cc < 512; cc += 256) {
                float a = 0.f;
                for (int j = 0; j < 60; ++j) a += aw[j] * ctxL[j * 516 + cc];
                gstll(&app_p[8 + bid * 512 + cc], packfe(a, s + 1));
            }
            __syncthreads();
        } else {
            {   // gh = gWhh @ h ; k = 4sg + 32j + r (broadcast LDS reads)
                float a = 0.f;
#pragma unroll
                for (int j = 0; j < 16; ++j) {
                    float4 w = wg4[j];
                    float4 h4 = *(const float4*)&hx[8 + 4 * sg + 32 * j];
                    a += w.x*h4.x + w.y*h4.y + w.z*h4.z + w.w*h4.w;
                }
                redG[rg][sg] = a;
            }
            __syncthreads();
            if (tid < 24) {
                float a = biasg[tid];
#pragma unroll
                for (int g2 = 0; g2 < 8; ++g2) a += redG[tid][g2];
                ghl[tid] = a;
            }
            // ---- hop 2: inp+applied (epoch s+1) ----
            for (int c = tid; c < 1032; c += 256)
                xl[c] = waitfe(&app_p[c], s + 1);
            __syncthreads();
            {   // o = relu(comb_W @ [inp; applied]) ; k = 4sc + 128i + r
                float b = 0.f;
#pragma unroll
                for (int i = 0; i < 9; ++i) {
                    float4 w = wc4[i];
                    float4 x4 = *(const float4*)&xl[4 * sc + 128 * i];
                    b += w.x*x4.x + w.y*x4.y + w.z*x4.z + w.w*x4.w;
                }
                redC[rc][sc] = b;
            }
            __syncthreads();
            if (tid < 8) {
                float a = biasc[tid];
#pragma unroll
                for (int g2 = 0; g2 < 32; ++g2) a += redC[tid][g2];
                gstll(&obuf_p[dbase + tid], packfe(fmaxf(a, 0.f), s + 1));
            }
            // ---- hop 3: o all-gather (epoch s+1) ----
            for (int c = tid; c < 512; c += 256)
                xl[c] = waitfe(&obuf_p[c], s + 1);
            __syncthreads();
            {   // gi = gWih @ o
                float a = 0.f;
#pragma unroll
                for (int j = 0; j < 16; ++j) {
                    float4 w = wi4[j];
                    float4 o4 = *(const float4*)&xl[4 * sg + 32 * j];
                    a += w.x*o4.x + w.y*o4.y + w.z*o4.z + w.w*o4.w;
                }
                redG[rg][sg] = a;
            }
            __syncthreads();
            if (tid < 24) {
                float a = biasi[tid];
#pragma unroll
                for (int g2 = 0; g2 < 8; ++g2) a += redG[tid][g2];
                gil[tid] = a;
            }
            __syncthreads();
            if (tid < 8) {
                float r_ = sigf(gil[tid] + ghl[tid]);
                float z_ = sigf(gil[8 + tid] + ghl[8 + tid]);
                float n_ = tanh_f(gil[16 + tid] + r_ * ghl[16 + tid]);
                float hnew = (1.f - z_) * n_ + z_ * hx[8 + dbase + tid];
                gstll(&hdec_p[dbase + tid], packfe(hnew, s + 1));
            }
            __syncthreads();   // protect hx before next-step overwrite
        }
    }

    // epilogue: logits for s=29 (block 0)
    if (bid == 0) {
        for (int c = tid; c < 512; c += 256)
            hx[8 + c] = waitfe(&hdec_p[c], 30);
        __syncthreads();
        {
            float a = 0.f;
#pragma unroll
            for (int i = 0; i < 4; ++i) {
                float4 w = wo4[i];
                float4 h4 = *(const float4*)&hx[8 + 4 * so + 128 * i];
                a += w.x*h4.x + w.y*h4.y + w.z*h4.z + w.w*h4.w;
            }
            redO[ro][so] = a;
        }
        __syncthreads();
        if (tid < 8) {
            float a = outb[tid];
#pragma unroll
            for (int g2 = 0; g2 < 32; ++g2) a += redO[tid][g2];
            zd[tid] = a;
        }
        __syncthreads();
        if (tid == 0) {
            float m = zd[0];
            for (int l = 1; l < 8; ++l) m = fmaxf(m, zd[l]);
            float ss = 0.f;
            for (int l = 0; l < 8; ++l) ss += __expf(zd[l] - m);
            ms[0] = m + __logf(ss);
        }
        __syncthreads();
        if (tid < 8) dout[29 * 8 + tid] = zd[tid] - ms[0];
    }
}

// ---------------------------------------------------------------------------
extern "C" void kernel_launch(void* const* d_in, const int* in_sizes, int n_in,
                              void* d_out, int out_size, void* d_ws, size_t ws_size,
                              hipStream_t stream) {
    (void)in_sizes; (void)n_in; (void)out_size; (void)ws_size;
    const float* data    = (const float*)d_in[0];
    const float* enc_Wih = (const float*)d_in[1];
    const float* enc_Whh = (const float*)d_in[2];
    const float* enc_bih = (const float*)d_in[3];
    const float* enc_bhh = (const float*)d_in[4];
    const float* p1f_Wih = (const float*)d_in[5];
    const float* p1f_Whh = (const float*)d_in[6];
    const float* p1f_bih = (const float*)d_in[7];
    const float* p1f_bhh = (const float*)d_in[8];
    const float* p1b_Wih = (const float*)d_in[9];
    const float* p1b_Whh = (const float*)d_in[10];
    const float* p1b_bih = (const float*)d_in[11];
    const float* p1b_bhh = (const float*)d_in[12];
    const float* p2f_Wih = (const float*)d_in[13];
    const float* p2f_Whh = (const float*)d_in[14];
    const float* p2f_bih = (const float*)d_in[15];
    const float* p2f_bhh = (const float*)d_in[16];
    const float* p2b_Wih = (const float*)d_in[17];
    const float* p2b_Whh = (const float*)d_in[18];
    const float* p2b_bih = (const float*)d_in[19];
    const float* p2b_bhh = (const float*)d_in[20];
    const float* attn_W  = (const float*)d_in[21];
    const float* attn_b  = (const float*)d_in[22];
    const float* comb_W  = (const float*)d_in[23];
    const float* comb_b  = (const float*)d_in[24];
    const float* gru_Wih = (const float*)d_in[25];
    const float* gru_Whh = (const float*)d_in[26];
    const float* gru_bih = (const float*)d_in[27];
    const float* gru_bhh = (const float*)d_in[28];
    const float* out_W   = (const float*)d_in[29];
    const float* out_b   = (const float*)d_in[30];

    float* ws = (float*)d_ws;
    // zeroed region [0 .. 142864)
    ull* hbufF   = (ull*)ws;                 // 122880 floats (61440 ull)
    int* flagsE  = (int*)(ws + 122880);      // 7680
    ull* hp1     = (ull*)(ws + 130560);      // 4096 floats = [2][2][512] ull
    ull* hp2     = (ull*)(ws + 134656);      // 4096 floats
    ull* hdec_p  = (ull*)(ws + 138752);      // 1024 floats = 512 ull
    ull* app_p   = (ull*)(ws + 139776);      // 2064 floats = 1032 ull
    ull* obuf_p  = (ull*)(ws + 141840);      // 1024 floats = 512 ull -> end 142864
    // non-zeroed scratch
    float* henc  = ws + 142864;              // 122880
    float* xp1f  = ws + 265744;              // 245760
    float* xp1b  = ws + 511504;              // 245760
    float* f1    = ws + 757264;              // 61440
    float* b1o   = ws + 818704;              // 61440
    float* x2    = ws + 880144;              // 122880
    float* xp2f  = ws + 1003024;             // 122880
    float* xp2b  = ws + 1125904;             // 122880
    float* f2    = ws + 1248784;             // 30720
    float* b2o   = ws + 1279504;             // 30720
    float* ctxb  = ws + 1310224;             // 61440

    init_k<<<256, 256, 0, stream>>>(ws);

    enc_all<<<240, 256, 0, stream>>>(data, enc_Wih, enc_Whh, enc_bih, enc_bhh,
                                     hbufF, henc, flagsE);
    gemm_xp<<<128, 256, 0, stream>>>(henc, 120, 1024, 0, p1f_Wih, p1f_bih, p1f_bhh, xp1f);
    gemm_xp<<<128, 256, 0, stream>>>(henc, 120, 1024, 1, p1b_Wih, p1b_bih, p1b_bhh, xp1b);
    pyr_rec<<<128, 256, 0, stream>>>(xp1f, xp1b, p1f_Whh, p1b_Whh, hp1, f1, b1o, 120);
    x2_assemble<<<60, 256, 0, stream>>>(f1, b1o, x2);
    gemm_xp<<<64, 256, 0, stream>>>(x2, 60, 2048, 0, p2f_Wih, p2f_bih, p2f_bhh, xp2f);
    gemm_xp<<<64, 256, 0, stream>>>(x2, 60, 2048, 1, p2b_Wih, p2b_bih, p2b_bhh, xp2b);
    pyr_rec<<<128, 256, 0, stream>>>(xp2f, xp2b, p2f_Whh, p2b_Whh, hp2, f2, b2o, 60);
    ctx_k<<<60, 256, 0, stream>>>(f2, b2o, ctxb, hdec_p);
    dec_k<<<66, 256, 0, stream>>>(attn_W, attn_b, comb_W, comb_b,
                                  gru_Wih, gru_Whh, gru_bih, gru_bhh,
                                  out_W, out_b, ctxb, hdec_p, app_p, obuf_p,
                                  (float*)d_out);
}